// Round 6
// baseline (133.005 us; speedup 1.0000x reference)
//
#include <hip/hip_runtime.h>
#include <stdint.h>
#include <stddef.h>

#define DEV __device__ __forceinline__

typedef __attribute__((ext_vector_type(4))) float f32x4;
typedef __attribute__((ext_vector_type(8))) short bf16x8;

union FragU { bf16x8 f; uint32_t u[4]; };

DEV uint32_t pk_bf16(float a, float b) {
  uint32_t d;
  asm("v_cvt_pk_bf16_f32 %0, %1, %2" : "=v"(d) : "v"(a), "v"(b));
  return d;
}

DEV uint16_t f2bf(float x) {  // round-to-nearest-even
  uint32_t u = __float_as_uint(x);
  u += 0x7fffu + ((u >> 16) & 1u);
  return (uint16_t)(u >> 16);
}

// ---------------------------------------------------------------------------
// kP: bid<256: q/k/v GEMV (4 rows/block); bid 256: Ww1 -> bf16 frag order,
//     Ww2*log2e -> bf16 frag order; bid 257: analytic BN1 -> a1 + counter
//     reset.
// ---------------------------------------------------------------------------
__launch_bounds__(256)
__global__ void kP(const float* __restrict__ cf, const float* __restrict__ pos,
                   const float* __restrict__ Wq, const float* __restrict__ Wk,
                   const float* __restrict__ Wv, const float* __restrict__ bq,
                   const float* __restrict__ bk, const float* __restrict__ bv,
                   const float* __restrict__ Ww1, const float* __restrict__ Ww2,
                   const float* __restrict__ Wp1, const float* __restrict__ g_p,
                   const float* __restrict__ bp2,
                   float* __restrict__ qo, float* __restrict__ ko,
                   float* __restrict__ vT, uint16_t* __restrict__ W1bf,
                   uint16_t* __restrict__ W2bf, float* __restrict__ a1out,
                   unsigned int* __restrict__ counter) {
  const int bid = blockIdx.x, t = threadIdx.x;
  if (bid < 256) {
    __shared__ float cfl[4][64];
    const int rr = t >> 6, c = t & 63;
    const int r0 = bid * 4;
    cfl[rr][c] = cf[(size_t)(r0 + rr) * 64 + c];
    __syncthreads();
    const int bn = r0 + rr;
    const float* wqr = Wq + c * 64;
    const float* wkr = Wk + c * 64;
    const float* wvr = Wv + c * 64;
    float aq = bq[c], ak = bk[c], av = bv[c] + bp2[c];
#pragma unroll 8
    for (int kk = 0; kk < 64; ++kk) {
      const float f = cfl[rr][kk];
      aq = fmaf(f, wqr[kk], aq);
      ak = fmaf(f, wkr[kk], ak);
      av = fmaf(f, wvr[kk], av);
    }
    qo[(size_t)bn * 64 + c] = aq;
    ko[(size_t)bn * 64 + c] = ak;
    vT[((size_t)(bn >> 9) * 64 + c) * 512 + (bn & 511)] = av;
  } else if (bid == 256) {
    const float L2E = 1.4426950408889634f;
    // frag order: idx = ((nt*2+ks)*64 + lane)*8 + e
    for (int idx = t; idx < 8192; idx += 256) {
      const int m = idx >> 12;
      const int r = idx & 4095;
      const int f = r >> 9;
      const int l = (r >> 3) & 63;
      const int e = r & 7;
      const int nt = f >> 1, ks = f & 1, lm = l & 15, lq = l >> 4;
      const int row = 16 * nt + lm, col = 8 * lq + 32 * ks + e;
      const float src = m ? (Ww2[row * 64 + col] * L2E) : Ww1[row * 64 + col];
      (m ? W2bf : W1bf)[r] = f2bf(src);
    }
  } else {
    if (t == 0) counter[0] = 0u;
    __shared__ float acc9[2][9];
    __shared__ float red[256][10];
    __shared__ float red2[9][16];
    for (int b = 0; b < 2; ++b) {
      float s[9];
#pragma unroll
      for (int a = 0; a < 9; ++a) s[a] = 0.f;
      for (int r = 0; r < 2; ++r) {
        int i = t + 256 * r;
        const float* p = pos + (size_t)(b * 512 + i) * 3;
        float p0 = p[0], p1 = p[1], p2 = p[2];
        s[0] += p0; s[1] += p1; s[2] += p2;
        s[3] += p0 * p0; s[4] += p0 * p1; s[5] += p0 * p2;
        s[6] += p1 * p1; s[7] += p1 * p2; s[8] += p2 * p2;
      }
#pragma unroll
      for (int a = 0; a < 9; ++a) red[t][a] = s[a];
      __syncthreads();
      if (t < 144) {
        const int a = t >> 4, p = t & 15;
        float v = 0.f;
#pragma unroll
        for (int qq = 0; qq < 16; ++qq) v += red[p * 16 + qq][a];
        red2[a][p] = v;
      }
      __syncthreads();
      if (t < 9) {
        float v = 0.f;
#pragma unroll
        for (int p = 0; p < 16; ++p) v += red2[t][p];
        acc9[b][t] = v;
      }
      __syncthreads();
    }
    if (t == 0) {
      float C[6] = {0.f, 0.f, 0.f, 0.f, 0.f, 0.f};
      const float invM = 1.0f / 524288.0f;
      for (int b = 0; b < 2; ++b) {
        float S0 = acc9[b][0], S1 = acc9[b][1], S2 = acc9[b][2];
        float G00 = acc9[b][3], G01 = acc9[b][4], G02 = acc9[b][5];
        float G11 = acc9[b][6], G12 = acc9[b][7], G22 = acc9[b][8];
        C[0] += 1024.f * G00 - 2.f * S0 * S0;
        C[1] += 1024.f * G01 - 2.f * S0 * S1;
        C[2] += 1024.f * G02 - 2.f * S0 * S2;
        C[3] += 1024.f * G11 - 2.f * S1 * S1;
        C[4] += 1024.f * G12 - 2.f * S1 * S2;
        C[5] += 1024.f * G22 - 2.f * S2 * S2;
      }
      for (int a = 0; a < 6; ++a) C[a] *= invM;
      for (int tt = 0; tt < 3; ++tt) {
        float w0 = Wp1[tt * 3 + 0], w1 = Wp1[tt * 3 + 1], w2 = Wp1[tt * 3 + 2];
        float var = w0 * w0 * C[0] + w1 * w1 * C[3] + w2 * w2 * C[5]
                  + 2.f * (w0 * w1 * C[1] + w0 * w2 * C[2] + w1 * w2 * C[4]);
        a1out[tt] = g_p[tt] * rsqrtf(var + 1e-5f);
      }
      a1out[3] = 0.f;
    }
  }
}

// ---------------------------------------------------------------------------
// kB: 32 blocks (s,b,chunk), per-block complete R/C + folded partials; last
// block assembles a2/be2/PtT from partials only. (Validated round-5 version.)
// ---------------------------------------------------------------------------
__launch_bounds__(256)
__global__ void kB(const float* __restrict__ pos, const float* __restrict__ a1,
                   const float* __restrict__ Wp1, const float* __restrict__ b_p,
                   const float* __restrict__ q, const float* __restrict__ k,
                   const float* __restrict__ bp2,
                   const float* __restrict__ g_w, const float* __restrict__ b_w,
                   const float* __restrict__ Wp2,
                   float* __restrict__ hpa, float* __restrict__ Mpart,
                   float* __restrict__ XPp, float* __restrict__ SNp,
                   unsigned int* __restrict__ counter,
                   float* __restrict__ a2o, float* __restrict__ be2o,
                   float* __restrict__ PtT) {
  const int bid = blockIdx.x, t = threadIdx.x;
  const int s = bid >> 4, b = (bid >> 3) & 1, chunk = bid & 7;

  __shared__ __align__(16) f32x4 X[512];
  __shared__ float U[64][64];
  __shared__ float redr[64][4][4];
  __shared__ float mred[256][6];
  __shared__ float mred2[64][6];
  __shared__ float rfin[64][4];
  __shared__ float redn[256][2];
  __shared__ float MfS[6];
  __shared__ float ShfS[3];
  __shared__ unsigned int isLast;

  {
    const float a10 = a1[0], a11 = a1[1], a12 = a1[2];
    const float w00 = Wp1[0], w01 = Wp1[1], w02 = Wp1[2];
    const float w10 = Wp1[3], w11 = Wp1[4], w12 = Wp1[5];
    const float w20 = Wp1[6], w21 = Wp1[7], w22 = Wp1[8];
    for (int r = 0; r < 2; ++r) {
      const int row = t + 256 * r;
      const float* p = pos + (size_t)(b * 512 + row) * 3;
      const float p0 = p[0], p1 = p[1], p2 = p[2];
      f32x4 v;
      v.x = a10 * (w00 * p0 + w01 * p1 + w02 * p2);
      v.y = a11 * (w10 * p0 + w11 * p1 + w12 * p2);
      v.z = a12 * (w20 * p0 + w21 * p1 + w22 * p2);
      v.w = 0.f;
      if (s == 0 && chunk == 0)
        *(f32x4*)(hpa + (size_t)(b * 512 + row) * 4) = v;
      if (s) { v.x = -v.x; v.y = -v.y; v.z = -v.z; }
      X[row] = v;
    }
  }
  {
    const float* src = s ? k : q;
    const int r0g = b * 512 + chunk * 64;
#pragma unroll
    for (int e = 0; e < 16; ++e) {
      const int idx = e * 256 + t;
      const int row = idx >> 6, c = idx & 63;
      float v = src[(size_t)(r0g + row) * 64 + c];
      if (!s) v += bp2[c];
      U[row][c] = v;
    }
  }
  __syncthreads();

  {
    const int al = t >> 2, qr = t & 3;
    const int a = chunk * 64 + al;
    const f32x4 xa = X[a];
    const float base0 = xa.x + b_p[0], base1 = xa.y + b_p[1], base2 = xa.z + b_p[2];
    float r0 = 0, r1 = 0, r2 = 0;
    float m00 = 0, m01 = 0, m02 = 0, m11 = 0, m12 = 0, m22 = 0;
#pragma unroll 8
    for (int jj = qr * 128; jj < qr * 128 + 128; ++jj) {
      const f32x4 xj = X[jj];
      const float h0 = fmaxf(0.f, base0 - xj.x);
      const float h1 = fmaxf(0.f, base1 - xj.y);
      const float h2 = fmaxf(0.f, base2 - xj.z);
      r0 += h0; r1 += h1; r2 += h2;
      if (s == 0) {
        m00 = fmaf(h0, h0, m00); m01 = fmaf(h0, h1, m01); m02 = fmaf(h0, h2, m02);
        m11 = fmaf(h1, h1, m11); m12 = fmaf(h1, h2, m12); m22 = fmaf(h2, h2, m22);
      }
    }
    redr[al][qr][0] = r0; redr[al][qr][1] = r1; redr[al][qr][2] = r2; redr[al][qr][3] = 0.f;
    mred[t][0] = m00; mred[t][1] = m01; mred[t][2] = m02;
    mred[t][3] = m11; mred[t][4] = m12; mred[t][5] = m22;
  }
  __syncthreads();

  if (t < 64) {
    float sx = 0, sy = 0, sz = 0;
#pragma unroll
    for (int p = 0; p < 4; ++p) { sx += redr[t][p][0]; sy += redr[t][p][1]; sz += redr[t][p][2]; }
    rfin[t][0] = sx; rfin[t][1] = sy; rfin[t][2] = sz; rfin[t][3] = 0.f;
    if (s == 0) {
#pragma unroll
      for (int cc = 0; cc < 6; ++cc)
        mred2[t][cc] = mred[t][cc] + mred[t + 64][cc] + mred[t + 128][cc] + mred[t + 192][cc];
    }
  }
  __syncthreads();

  if (s == 0 && t < 6) {
    float m = 0.f;
    for (int p = 0; p < 64; ++p) m += mred2[p][t];
    Mpart[bid * 12 + t] = m;
  }
  if (s == 0 && t >= 64 && t < 67) {
    const int tt = t - 64;
    float v = 0.f;
#pragma unroll 8
    for (int a = 0; a < 64; ++a) v += rfin[a][tt];
    Mpart[bid * 12 + 6 + tt] = v;
  }
  if (t < 192) {
    const int c = t & 63, tt = t >> 6;
    float xp = 0.f;
#pragma unroll 8
    for (int a = 0; a < 64; ++a) xp = fmaf(U[a][c], rfin[a][tt], xp);
    if (s) xp = -xp;
    XPp[((size_t)bid * 3 + tt) * 64 + c] = xp;
  }
  {
    const int c = t & 63, g = t >> 6;
    float su = 0.f, su2 = 0.f;
#pragma unroll
    for (int r = 0; r < 16; ++r) {
      const float v = U[g * 16 + r][c];
      su += v;
      su2 = fmaf(v, v, su2);
    }
    redn[t][0] = su; redn[t][1] = su2;
  }
  __syncthreads();
  if (t < 64) {
    float a0 = 0.f, a1v = 0.f;
#pragma unroll
    for (int p = 0; p < 4; ++p) { a0 += redn[t + 64 * p][0]; a1v += redn[t + 64 * p][1]; }
    SNp[((size_t)bid * 2 + 0) * 64 + t] = a0;
    SNp[((size_t)bid * 2 + 1) * 64 + t] = a1v;
  }

  __syncthreads();
  if (t == 0) {
    __threadfence();
    const unsigned int old = atomicAdd(counter, 1u);
    isLast = (old == 31u) ? 1u : 0u;
  }
  __syncthreads();
  if (isLast) {
    __threadfence();
    if (t < 6) {
      float m = 0.f;
#pragma unroll
      for (int p = 0; p < 16; ++p) m += Mpart[p * 12 + t];
      MfS[t] = m;
    }
    if (t >= 6 && t < 9) {
      const int tt = t - 6;
      float v = 0.f;
#pragma unroll
      for (int p = 0; p < 16; ++p) v += Mpart[p * 12 + 6 + tt];
      ShfS[tt] = v;
    }
    __syncthreads();
    if (t < 64) {
      const int c = t;
      float Su[2], Su2[2], Sk[2], Sk2[2];
#pragma unroll
      for (int bb = 0; bb < 2; ++bb) {
        float a0 = 0.f, a1v = 0.f, a2v = 0.f, a3 = 0.f;
#pragma unroll
        for (int p = 0; p < 8; ++p) {
          const int blkU = bb * 8 + p;
          const int blkK = 16 + bb * 8 + p;
          a0 += SNp[((size_t)blkU * 2 + 0) * 64 + c];
          a1v += SNp[((size_t)blkU * 2 + 1) * 64 + c];
          a2v += SNp[((size_t)blkK * 2 + 0) * 64 + c];
          a3 += SNp[((size_t)blkK * 2 + 1) * 64 + c];
        }
        Su[bb] = a0; Su2[bb] = a1v; Sk[bb] = a2v; Sk2[bb] = a3;
      }
      float URd0 = 0.f, URd1 = 0.f, URd2 = 0.f;
#pragma unroll
      for (int blk = 0; blk < 32; ++blk) {
        URd0 += XPp[((size_t)blk * 3 + 0) * 64 + c];
        URd1 += XPp[((size_t)blk * 3 + 1) * 64 + c];
        URd2 += XPp[((size_t)blk * 3 + 2) * 64 + c];
      }
      const float P0t = Wp2[c * 3 + 0], P1t = Wp2[c * 3 + 1], P2t = Wp2[c * 3 + 2];
      const float Nf = 512.f, invM = 1.f / 524288.f;
      float S1 = 0.f, Q2 = 0.f;
#pragma unroll
      for (int bb = 0; bb < 2; ++bb) {
        S1 += Nf * (Su[bb] - Sk[bb]);
        Q2 += Nf * Su2[bb] - 2.f * Su[bb] * Sk[bb] + Nf * Sk2[bb];
      }
      const float Xc = P0t * URd0 + P1t * URd1 + P2t * URd2;
      S1 += P0t * ShfS[0] + P1t * ShfS[1] + P2t * ShfS[2];
      const float Hm = P0t * P0t * MfS[0] + 2.f * P0t * P1t * MfS[1] + 2.f * P0t * P2t * MfS[2]
                     + P1t * P1t * MfS[3] + 2.f * P1t * P2t * MfS[4] + P2t * P2t * MfS[5];
      const float E1 = S1 * invM;
      const float E2 = (Q2 + 2.f * Xc + Hm) * invM;
      const float var = E2 - E1 * E1;
      const float rstd = rsqrtf(var + 1e-5f);
      const float A2 = g_w[c] * rstd;
      a2o[c] = A2;
      be2o[c] = b_w[c] - E1 * A2;
      PtT[0 * 64 + c] = A2 * P0t;
      PtT[1 * 64 + c] = A2 * P1t;
      PtT[2 * 64 + c] = A2 * P2t;
    }
  }
}

// ---------------------------------------------------------------------------
// k3: fused main, 2 i's per block sharing all j-side loads, j-range split in
// half (grid 1024), biases folded into MFMA C-init, W2 (log2e-scaled) frags
// from global/L1, partial (L,A) out.
// ---------------------------------------------------------------------------
__launch_bounds__(256, 4)
__global__ void k3_main(const float* __restrict__ q, const float* __restrict__ kk_,
                        const float* __restrict__ vT, const float* __restrict__ hpa,
                        const float* __restrict__ a2g, const float* __restrict__ be2g,
                        const float* __restrict__ PtTg,
                        const uint16_t* __restrict__ W1bf, const uint16_t* __restrict__ W2bf,
                        const float* __restrict__ bp2, const float* __restrict__ Wp2,
                        const float* __restrict__ b_p, const float* __restrict__ bw1g,
                        const float* __restrict__ bw2g, float* __restrict__ Pout) {
  const int bid = blockIdx.x;
  const int b = bid >> 9, rem = bid & 511;
  const int ipair = rem >> 1, half = rem & 1;
  const int i0 = ipair * 2;
  const int t = threadIdx.x;
  const int wid = t >> 6, l = t & 63;
  const int lm = l & 15, lq = l >> 4;

  __shared__ __align__(16) uint16_t W1l[4096];
  __shared__ __align__(16) uint16_t H2[4][2][16][76];
  __shared__ __align__(16) float P0L[2][64];
  __shared__ __align__(16) float a2s[64];
  __shared__ __align__(16) float Pts[3][64];
  __shared__ __align__(16) float comb[4][2][64][2];

  *(bf16x8*)(&W1l[t * 16])     = *(const bf16x8*)(W1bf + t * 16);
  *(bf16x8*)(&W1l[t * 16 + 8]) = *(const bf16x8*)(W1bf + t * 16 + 8);
  if (t < 128) {
    const int ii = t >> 6, c = t & 63;
    P0L[ii][c] = fmaf(a2g[c], q[(size_t)(b * 512 + i0 + ii) * 64 + c] + bp2[c], be2g[c]);
  } else if (t < 192) {
    const int c = t - 128;
    a2s[c] = a2g[c];
  } else {
    const int c = t - 192;
    Pts[0][c] = PtTg[c];
    Pts[1][c] = PtTg[64 + c];
    Pts[2][c] = PtTg[128 + c];
  }

  const f32x4 hi0 = *(const f32x4*)(hpa + (size_t)(b * 512 + i0) * 4);
  const f32x4 hi1 = *(const f32x4*)(hpa + (size_t)(b * 512 + i0 + 1) * 4);
  const float bb0 = b_p[0], bb1 = b_p[1], bb2 = b_p[2];
  const float LOG2E = 1.4426950408889634f;

  float bw1r[4], bw2l[4], wpa[4], wpb[4], wpc[4];
#pragma unroll
  for (int nt = 0; nt < 4; ++nt) {
    const int c = 16 * nt + lm;
    bw1r[nt] = bw1g[c];
    bw2l[nt] = bw2g[c] * LOG2E;
    wpa[nt] = Wp2[c * 3 + 0];
    wpb[nt] = Wp2[c * 3 + 1];
    wpc[nt] = Wp2[c * 3 + 2];
  }

  float l0_[4] = {0.f, 0.f, 0.f, 0.f}, a0_[4] = {0.f, 0.f, 0.f, 0.f};
  float l1_[4] = {0.f, 0.f, 0.f, 0.f}, a1_[4] = {0.f, 0.f, 0.f, 0.f};

  __syncthreads();

  const float* kbase = kk_ + (size_t)(b * 512) * 64;
  const float* hbase = hpa + (size_t)(b * 512) * 4;
  const float* vTb = vT + (size_t)b * 64 * 512;

  for (int it = 0; it < 4; ++it) {
    const int jb = half * 256 + it * 64 + wid * 16;
    const int j = jb + lm;
    const int j2 = jb + 4 * lq;

    // k row + own-j hpa
    f32x4 kv[2][2];
#pragma unroll
    for (int ks = 0; ks < 2; ++ks) {
      kv[ks][0] = *(const f32x4*)(kbase + (size_t)j * 64 + 32 * ks + 8 * lq);
      kv[ks][1] = *(const f32x4*)(kbase + (size_t)j * 64 + 32 * ks + 8 * lq + 4);
    }
    const f32x4 hj = *(const f32x4*)(hbase + j * 4);

    const float h00 = fmaxf(0.f, hi0.x - hj.x + bb0);
    const float h01 = fmaxf(0.f, hi0.y - hj.y + bb1);
    const float h02 = fmaxf(0.f, hi0.z - hj.z + bb2);
    const float h10 = fmaxf(0.f, hi1.x - hj.x + bb0);
    const float h11 = fmaxf(0.f, hi1.y - hj.y + bb1);
    const float h12 = fmaxf(0.f, hi1.z - hj.z + bb2);

    // ---- stage A for both i's (shared -a2*k term) ----
    FragU A1a[2], A1b[2];
#pragma unroll
    for (int ks = 0; ks < 2; ++ks) {
      float x0[8], x1[8];
#pragma unroll
      for (int hh = 0; hh < 2; ++hh) {
        const int c0 = 32 * ks + 8 * lq + 4 * hh;
        const f32x4 av = *(const f32x4*)(a2s + c0);
        const f32x4 t0v = *(const f32x4*)(&Pts[0][c0]);
        const f32x4 t1v = *(const f32x4*)(&Pts[1][c0]);
        const f32x4 t2v = *(const f32x4*)(&Pts[2][c0]);
        const f32x4 p0v = *(const f32x4*)(&P0L[0][c0]);
        const f32x4 p1v = *(const f32x4*)(&P0L[1][c0]);
#pragma unroll
        for (int e = 0; e < 4; ++e) {
          const float nak = -av[e] * kv[ks][hh][e];
          float xv0 = p0v[e] + nak;
          xv0 = fmaf(t0v[e], h00, xv0);
          xv0 = fmaf(t1v[e], h01, xv0);
          xv0 = fmaf(t2v[e], h02, xv0);
          x0[4 * hh + e] = fmaxf(0.f, xv0);
          float xv1 = p1v[e] + nak;
          xv1 = fmaf(t0v[e], h10, xv1);
          xv1 = fmaf(t1v[e], h11, xv1);
          xv1 = fmaf(t2v[e], h12, xv1);
          x1[4 * hh + e] = fmaxf(0.f, xv1);
        }
      }
      A1a[ks].u[0] = pk_bf16(x0[0], x0[1]);
      A1a[ks].u[1] = pk_bf16(x0[2], x0[3]);
      A1a[ks].u[2] = pk_bf16(x0[4], x0[5]);
      A1a[ks].u[3] = pk_bf16(x0[6], x0[7]);
      A1b[ks].u[0] = pk_bf16(x1[0], x1[1]);
      A1b[ks].u[1] = pk_bf16(x1[2], x1[3]);
      A1b[ks].u[2] = pk_bf16(x1[4], x1[5]);
      A1b[ks].u[3] = pk_bf16(x1[6], x1[7]);
    }

    // ---- GEMM1 both (shared W1 frags, bias in C-init) ----
    f32x4 d1a[4], d1b[4];
#pragma unroll
    for (int nt = 0; nt < 4; ++nt) {
      FragU w0, w1;
      w0.f = *(const bf16x8*)(&W1l[((nt * 2 + 0) * 64 + l) * 8]);
      w1.f = *(const bf16x8*)(&W1l[((nt * 2 + 1) * 64 + l) * 8]);
      f32x4 z0 = {bw1r[nt], bw1r[nt], bw1r[nt], bw1r[nt]};
      z0 = __builtin_amdgcn_mfma_f32_16x16x32_bf16(A1a[0].f, w0.f, z0, 0, 0, 0);
      z0 = __builtin_amdgcn_mfma_f32_16x16x32_bf16(A1a[1].f, w1.f, z0, 0, 0, 0);
      d1a[nt] = z0;
      f32x4 z1 = {bw1r[nt], bw1r[nt], bw1r[nt], bw1r[nt]};
      z1 = __builtin_amdgcn_mfma_f32_16x16x32_bf16(A1b[0].f, w0.f, z1, 0, 0, 0);
      z1 = __builtin_amdgcn_mfma_f32_16x16x32_bf16(A1b[1].f, w1.f, z1, 0, 0, 0);
      d1b[nt] = z1;
    }

    // ---- relu + repack both to per-wave LDS tiles ----
    {
      uint16_t (*h2w)[76] = H2[wid][0];
#pragma unroll
      for (int nt = 0; nt < 4; ++nt) {
        const uint32_t u01 = pk_bf16(fmaxf(0.f, d1a[nt][0]), fmaxf(0.f, d1a[nt][1]));
        const uint32_t u23 = pk_bf16(fmaxf(0.f, d1a[nt][2]), fmaxf(0.f, d1a[nt][3]));
        const int col = 16 * nt + lm;
        h2w[4 * lq + 0][col] = (uint16_t)(u01 & 0xffffu);
        h2w[4 * lq + 1][col] = (uint16_t)(u01 >> 16);
        h2w[4 * lq + 2][col] = (uint16_t)(u23 & 0xffffu);
        h2w[4 * lq + 3][col] = (uint16_t)(u23 >> 16);
      }
    }
    {
      uint16_t (*h2w)[76] = H2[wid][1];
#pragma unroll
      for (int nt = 0; nt < 4; ++nt) {
        const uint32_t u01 = pk_bf16(fmaxf(0.f, d1b[nt][0]), fmaxf(0.f, d1b[nt][1]));
        const uint32_t u23 = pk_bf16(fmaxf(0.f, d1b[nt][2]), fmaxf(0.f, d1b[nt][3]));
        const int col = 16 * nt + lm;
        h2w[4 * lq + 0][col] = (uint16_t)(u01 & 0xffffu);
        h2w[4 * lq + 1][col] = (uint16_t)(u01 >> 16);
        h2w[4 * lq + 2][col] = (uint16_t)(u23 & 0xffffu);
        h2w[4 * lq + 3][col] = (uint16_t)(u23 >> 16);
      }
    }

    FragU A2a[2], A2b[2];
    A2a[0].f = *(const bf16x8*)(&H2[wid][0][lm][8 * lq]);
    A2a[1].f = *(const bf16x8*)(&H2[wid][0][lm][32 + 8 * lq]);
    A2b[0].f = *(const bf16x8*)(&H2[wid][1][lm][8 * lq]);
    A2b[1].f = *(const bf16x8*)(&H2[wid][1][lm][32 + 8 * lq]);

    // ---- GEMM2 both (W2 frags from global/L1, bias(log2e) in C-init) ----
    f32x4 d2a[4], d2b[4];
#pragma unroll
    for (int nt = 0; nt < 4; ++nt) {
      FragU w0, w1;
      w0.f = *(const bf16x8*)(W2bf + ((nt * 2 + 0) * 64 + l) * 8);
      w1.f = *(const bf16x8*)(W2bf + ((nt * 2 + 1) * 64 + l) * 8);
      f32x4 z0 = {bw2l[nt], bw2l[nt], bw2l[nt], bw2l[nt]};
      z0 = __builtin_amdgcn_mfma_f32_16x16x32_bf16(A2a[0].f, w0.f, z0, 0, 0, 0);
      z0 = __builtin_amdgcn_mfma_f32_16x16x32_bf16(A2a[1].f, w1.f, z0, 0, 0, 0);
      d2a[nt] = z0;
      f32x4 z1 = {bw2l[nt], bw2l[nt], bw2l[nt], bw2l[nt]};
      z1 = __builtin_amdgcn_mfma_f32_16x16x32_bf16(A2b[0].f, w0.f, z1, 0, 0, 0);
      z1 = __builtin_amdgcn_mfma_f32_16x16x32_bf16(A2b[1].f, w1.f, z1, 0, 0, 0);
      d2b[nt] = z1;
    }

    // ---- j-side values (shared) + hr per i ----
    f32x4 vv[4];
#pragma unroll
    for (int nt = 0; nt < 4; ++nt)
      vv[nt] = *(const f32x4*)(vTb + (size_t)(16 * nt + lm) * 512 + j2);
    f32x4 hjr[4];
#pragma unroll
    for (int r = 0; r < 4; ++r) hjr[r] = *(const f32x4*)(hbase + (j2 + r) * 4);

    float hr00[4], hr01[4], hr02[4], hr10[4], hr11[4], hr12[4];
#pragma unroll
    for (int r = 0; r < 4; ++r) {
      hr00[r] = fmaxf(0.f, hi0.x - hjr[r].x + bb0);
      hr01[r] = fmaxf(0.f, hi0.y - hjr[r].y + bb1);
      hr02[r] = fmaxf(0.f, hi0.z - hjr[r].z + bb2);
      hr10[r] = fmaxf(0.f, hi1.x - hjr[r].x + bb0);
      hr11[r] = fmaxf(0.f, hi1.y - hjr[r].y + bb1);
      hr12[r] = fmaxf(0.f, hi1.z - hjr[r].z + bb2);
    }

    // ---- no-max softmax accumulation, both i's ----
#pragma unroll
    for (int nt = 0; nt < 4; ++nt) {
      float p0[4], p1[4], va[4], vb[4];
#pragma unroll
      for (int r = 0; r < 4; ++r) {
        p0[r] = __builtin_amdgcn_exp2f(d2a[nt][r]);
        p1[r] = __builtin_amdgcn_exp2f(d2b[nt][r]);
        const float vvr = vv[nt][r];
        float v0 = fmaf(wpa[nt], hr00[r], vvr);
        v0 = fmaf(wpb[nt], hr01[r], v0);
        v0 = fmaf(wpc[nt], hr02[r], v0);
        va[r] = v0;
        float v1 = fmaf(wpa[nt], hr10[r], vvr);
        v1 = fmaf(wpb[nt], hr11[r], v1);
        v1 = fmaf(wpc[nt], hr12[r], v1);
        vb[r] = v1;
      }
      l0_[nt] += (p0[0] + p0[1]) + (p0[2] + p0[3]);
      l1_[nt] += (p1[0] + p1[1]) + (p1[2] + p1[3]);
      float aa = a0_[nt];
      aa = fmaf(p0[0], va[0], aa); aa = fmaf(p0[1], va[1], aa);
      aa = fmaf(p0[2], va[2], aa); aa = fmaf(p0[3], va[3], aa);
      a0_[nt] = aa;
      float ab = a1_[nt];
      ab = fmaf(p1[0], vb[0], ab); ab = fmaf(p1[1], vb[1], ab);
      ab = fmaf(p1[2], vb[2], ab); ab = fmaf(p1[3], vb[3], ab);
      a1_[nt] = ab;
    }
  }

  // ---- combine within block ----
#pragma unroll
  for (int nt = 0; nt < 4; ++nt) {
    l0_[nt] += __shfl_xor(l0_[nt], 16); a0_[nt] += __shfl_xor(a0_[nt], 16);
    l0_[nt] += __shfl_xor(l0_[nt], 32); a0_[nt] += __shfl_xor(a0_[nt], 32);
    l1_[nt] += __shfl_xor(l1_[nt], 16); a1_[nt] += __shfl_xor(a1_[nt], 16);
    l1_[nt] += __shfl_xor(l1_[nt], 32); a1_[nt] += __shfl_xor(a1_[nt], 32);
  }
  if (lq == 0) {
#pragma unroll
    for (int nt = 0; nt < 4; ++nt) {
      comb[wid][0][16 * nt + lm][0] = l0_[nt];
      comb[wid][0][16 * nt + lm][1] = a0_[nt];
      comb[wid][1][16 * nt + lm][0] = l1_[nt];
      comb[wid][1][16 * nt + lm][1] = a1_[nt];
    }
  }
  __syncthreads();
  if (t < 128) {
    const int ii = t >> 6, c = t & 63;
    float L = 0.f, A = 0.f;
#pragma unroll
    for (int w = 0; w < 4; ++w) {
      L += comb[w][ii][c][0];
      A += comb[w][ii][c][1];
    }
    Pout[(size_t)bid * 256 + ii * 128 + c] = L;
    Pout[(size_t)bid * 256 + ii * 128 + 64 + c] = A;
  }
}

// ---------------------------------------------------------------------------
// k4: combine j-halves: out = (A0+A1)/(L0+L1)
// ---------------------------------------------------------------------------
__launch_bounds__(256)
__global__ void k4(const float* __restrict__ Pout, float* __restrict__ out) {
  const int g = blockIdx.x * 256 + threadIdx.x;
  const int row = g >> 6, c = g & 63;
  const int b = row >> 9, i = row & 511;
  const int ipair = i >> 1, sub = i & 1;
  const size_t base = (size_t)((b << 9) | (ipair << 1)) * 256 + sub * 128 + c;
  const float L = Pout[base] + Pout[base + 256];
  const float A = Pout[base + 64] + Pout[base + 320];
  out[(size_t)row * 64 + c] = A / L;
}

// ---------------------------------------------------------------------------
extern "C" void kernel_launch(void* const* d_in, const int* in_sizes, int n_in,
                              void* d_out, int out_size, void* d_ws, size_t ws_size,
                              hipStream_t stream) {
  (void)in_sizes; (void)n_in; (void)out_size; (void)ws_size;
  const float* pos = (const float*)d_in[0];
  const float* cf  = (const float*)d_in[1];
  const float* Wq  = (const float*)d_in[2];
  const float* bq  = (const float*)d_in[3];
  const float* Wk  = (const float*)d_in[4];
  const float* bk  = (const float*)d_in[5];
  const float* Wv  = (const float*)d_in[6];
  const float* bv  = (const float*)d_in[7];
  const float* Wp1 = (const float*)d_in[8];
  // d_in[9] = bp1: cancels analytically (gamma1 == b_p exactly)
  const float* g_p = (const float*)d_in[10];
  const float* b_p = (const float*)d_in[11];
  const float* Wp2 = (const float*)d_in[12];
  const float* bp2 = (const float*)d_in[13];
  const float* g_w = (const float*)d_in[14];
  const float* b_w = (const float*)d_in[15];
  const float* Ww1 = (const float*)d_in[16];
  const float* bw1 = (const float*)d_in[17];
  const float* Ww2 = (const float*)d_in[18];
  const float* bw2 = (const float*)d_in[19];

  char* ws = (char*)d_ws;
  uint16_t*     W1bf = (uint16_t*)(ws + 0);        // 8 KB
  uint16_t*     W2bf = (uint16_t*)(ws + 8192);     // 8 KB (log2e-scaled)
  float*        a1w  = (float*)(ws + 16384);
  unsigned int* cnt  = (unsigned int*)(ws + 16640);
  float*        hpaw = (float*)(ws + 16896);       // [1024][4]
  float*        qw   = (float*)(ws + 33280);       // [1024][64]
  float*        kw   = (float*)(ws + 295424);      // [1024][64]
  float*        vTw  = (float*)(ws + 557568);      // [2][64][512]
  float*        a2w  = (float*)(ws + 819712);
  float*        be2w = (float*)(ws + 819968);
  float*        PtTw = (float*)(ws + 820224);      // [3][64]
  float*        Mpw  = (float*)(ws + 821248);      // [32][12]
  float*        XPpw = (float*)(ws + 823040);      // [32][3][64]
  float*        SNpw = (float*)(ws + 847872);      // [32][2][64] -> end 864256
  float*        Pow  = (float*)(ws + 821248);      // [1024][256] — overlaps
                                                   // Mpw/XPpw/SNpw (dead after kB)

  kP<<<dim3(258), dim3(256), 0, stream>>>(cf, pos, Wq, Wk, Wv, bq, bk, bv,
                                          Ww1, Ww2, Wp1, g_p, bp2,
                                          qw, kw, vTw, W1bf, W2bf, a1w, cnt);
  kB<<<dim3(32), dim3(256), 0, stream>>>(pos, a1w, Wp1, b_p, qw, kw, bp2,
                                         g_w, b_w, Wp2,
                                         hpaw, Mpw, XPpw, SNpw, cnt,
                                         a2w, be2w, PtTw);
  k3_main<<<dim3(1024), dim3(256), 0, stream>>>(qw, kw, vTw, hpaw, a2w, be2w, PtTw,
                                                W1bf, W2bf, bp2, Wp2, b_p, bw1, bw2,
                                                Pow);
  k4<<<dim3(256), dim3(256), 0, stream>>>(Pow, (float*)d_out);
}

// Round 7
// 72.053 us; speedup vs baseline: 1.8459x; 1.8459x over previous
//
#include <hip/hip_runtime.h>
#include <stdint.h>
#include <stddef.h>

#define DEV __device__ __forceinline__

typedef __attribute__((ext_vector_type(4))) float f32x4;
typedef __attribute__((ext_vector_type(8))) short bf16x8;

union FragU { bf16x8 f; uint32_t u[4]; };

DEV uint32_t pk_bf16(float a, float b) {
  uint32_t d;
  asm("v_cvt_pk_bf16_f32 %0, %1, %2" : "=v"(d) : "v"(a), "v"(b));
  return d;
}

DEV uint16_t f2bf(float x) {  // round-to-nearest-even
  uint32_t u = __float_as_uint(x);
  u += 0x7fffu + ((u >> 16) & 1u);
  return (uint16_t)(u >> 16);
}

// ---------------------------------------------------------------------------
// kP: bid<256: q/k/v GEMV (4 rows/block); bid 256: Ww1 -> bf16 frag order,
//     Ww2*log2e -> bf16 frag order; bid 257: analytic BN1 -> a1 + counter
//     reset.
// ---------------------------------------------------------------------------
__launch_bounds__(256)
__global__ void kP(const float* __restrict__ cf, const float* __restrict__ pos,
                   const float* __restrict__ Wq, const float* __restrict__ Wk,
                   const float* __restrict__ Wv, const float* __restrict__ bq,
                   const float* __restrict__ bk, const float* __restrict__ bv,
                   const float* __restrict__ Ww1, const float* __restrict__ Ww2,
                   const float* __restrict__ Wp1, const float* __restrict__ g_p,
                   const float* __restrict__ bp2,
                   float* __restrict__ qo, float* __restrict__ ko,
                   float* __restrict__ vT, uint16_t* __restrict__ W1bf,
                   uint16_t* __restrict__ W2bf, float* __restrict__ a1out,
                   unsigned int* __restrict__ counter) {
  const int bid = blockIdx.x, t = threadIdx.x;
  if (bid < 256) {
    __shared__ float cfl[4][64];
    const int rr = t >> 6, c = t & 63;
    const int r0 = bid * 4;
    cfl[rr][c] = cf[(size_t)(r0 + rr) * 64 + c];
    __syncthreads();
    const int bn = r0 + rr;
    const float* wqr = Wq + c * 64;
    const float* wkr = Wk + c * 64;
    const float* wvr = Wv + c * 64;
    float aq = bq[c], ak = bk[c], av = bv[c] + bp2[c];
#pragma unroll 8
    for (int kk = 0; kk < 64; ++kk) {
      const float f = cfl[rr][kk];
      aq = fmaf(f, wqr[kk], aq);
      ak = fmaf(f, wkr[kk], ak);
      av = fmaf(f, wvr[kk], av);
    }
    qo[(size_t)bn * 64 + c] = aq;
    ko[(size_t)bn * 64 + c] = ak;
    vT[((size_t)(bn >> 9) * 64 + c) * 512 + (bn & 511)] = av;
  } else if (bid == 256) {
    const float L2E = 1.4426950408889634f;
    // frag order: idx = ((nt*2+ks)*64 + lane)*8 + e
    for (int idx = t; idx < 8192; idx += 256) {
      const int m = idx >> 12;
      const int r = idx & 4095;
      const int f = r >> 9;
      const int l = (r >> 3) & 63;
      const int e = r & 7;
      const int nt = f >> 1, ks = f & 1, lm = l & 15, lq = l >> 4;
      const int row = 16 * nt + lm, col = 8 * lq + 32 * ks + e;
      const float src = m ? (Ww2[row * 64 + col] * L2E) : Ww1[row * 64 + col];
      (m ? W2bf : W1bf)[r] = f2bf(src);
    }
  } else {
    if (t == 0) counter[0] = 0u;
    __shared__ float acc9[2][9];
    __shared__ float red[256][10];
    __shared__ float red2[9][16];
    for (int b = 0; b < 2; ++b) {
      float s[9];
#pragma unroll
      for (int a = 0; a < 9; ++a) s[a] = 0.f;
      for (int r = 0; r < 2; ++r) {
        int i = t + 256 * r;
        const float* p = pos + (size_t)(b * 512 + i) * 3;
        float p0 = p[0], p1 = p[1], p2 = p[2];
        s[0] += p0; s[1] += p1; s[2] += p2;
        s[3] += p0 * p0; s[4] += p0 * p1; s[5] += p0 * p2;
        s[6] += p1 * p1; s[7] += p1 * p2; s[8] += p2 * p2;
      }
#pragma unroll
      for (int a = 0; a < 9; ++a) red[t][a] = s[a];
      __syncthreads();
      if (t < 144) {
        const int a = t >> 4, p = t & 15;
        float v = 0.f;
#pragma unroll
        for (int qq = 0; qq < 16; ++qq) v += red[p * 16 + qq][a];
        red2[a][p] = v;
      }
      __syncthreads();
      if (t < 9) {
        float v = 0.f;
#pragma unroll
        for (int p = 0; p < 16; ++p) v += red2[t][p];
        acc9[b][t] = v;
      }
      __syncthreads();
    }
    if (t == 0) {
      float C[6] = {0.f, 0.f, 0.f, 0.f, 0.f, 0.f};
      const float invM = 1.0f / 524288.0f;
      for (int b = 0; b < 2; ++b) {
        float S0 = acc9[b][0], S1 = acc9[b][1], S2 = acc9[b][2];
        float G00 = acc9[b][3], G01 = acc9[b][4], G02 = acc9[b][5];
        float G11 = acc9[b][6], G12 = acc9[b][7], G22 = acc9[b][8];
        C[0] += 1024.f * G00 - 2.f * S0 * S0;
        C[1] += 1024.f * G01 - 2.f * S0 * S1;
        C[2] += 1024.f * G02 - 2.f * S0 * S2;
        C[3] += 1024.f * G11 - 2.f * S1 * S1;
        C[4] += 1024.f * G12 - 2.f * S1 * S2;
        C[5] += 1024.f * G22 - 2.f * S2 * S2;
      }
      for (int a = 0; a < 6; ++a) C[a] *= invM;
      for (int tt = 0; tt < 3; ++tt) {
        float w0 = Wp1[tt * 3 + 0], w1 = Wp1[tt * 3 + 1], w2 = Wp1[tt * 3 + 2];
        float var = w0 * w0 * C[0] + w1 * w1 * C[3] + w2 * w2 * C[5]
                  + 2.f * (w0 * w1 * C[1] + w0 * w2 * C[2] + w1 * w2 * C[4]);
        a1out[tt] = g_p[tt] * rsqrtf(var + 1e-5f);
      }
      a1out[3] = 0.f;
    }
  }
}

// ---------------------------------------------------------------------------
// kB: 32 blocks (s,b,chunk), per-block complete R/C + folded partials; last
// block assembles a2/be2/PtT from partials only. (Validated round-5 version.)
// ---------------------------------------------------------------------------
__launch_bounds__(256)
__global__ void kB(const float* __restrict__ pos, const float* __restrict__ a1,
                   const float* __restrict__ Wp1, const float* __restrict__ b_p,
                   const float* __restrict__ q, const float* __restrict__ k,
                   const float* __restrict__ bp2,
                   const float* __restrict__ g_w, const float* __restrict__ b_w,
                   const float* __restrict__ Wp2,
                   float* __restrict__ hpa, float* __restrict__ Mpart,
                   float* __restrict__ XPp, float* __restrict__ SNp,
                   unsigned int* __restrict__ counter,
                   float* __restrict__ a2o, float* __restrict__ be2o,
                   float* __restrict__ PtT) {
  const int bid = blockIdx.x, t = threadIdx.x;
  const int s = bid >> 4, b = (bid >> 3) & 1, chunk = bid & 7;

  __shared__ __align__(16) f32x4 X[512];
  __shared__ float U[64][64];
  __shared__ float redr[64][4][4];
  __shared__ float mred[256][6];
  __shared__ float mred2[64][6];
  __shared__ float rfin[64][4];
  __shared__ float redn[256][2];
  __shared__ float MfS[6];
  __shared__ float ShfS[3];
  __shared__ unsigned int isLast;

  {
    const float a10 = a1[0], a11 = a1[1], a12 = a1[2];
    const float w00 = Wp1[0], w01 = Wp1[1], w02 = Wp1[2];
    const float w10 = Wp1[3], w11 = Wp1[4], w12 = Wp1[5];
    const float w20 = Wp1[6], w21 = Wp1[7], w22 = Wp1[8];
    for (int r = 0; r < 2; ++r) {
      const int row = t + 256 * r;
      const float* p = pos + (size_t)(b * 512 + row) * 3;
      const float p0 = p[0], p1 = p[1], p2 = p[2];
      f32x4 v;
      v.x = a10 * (w00 * p0 + w01 * p1 + w02 * p2);
      v.y = a11 * (w10 * p0 + w11 * p1 + w12 * p2);
      v.z = a12 * (w20 * p0 + w21 * p1 + w22 * p2);
      v.w = 0.f;
      if (s == 0 && chunk == 0)
        *(f32x4*)(hpa + (size_t)(b * 512 + row) * 4) = v;
      if (s) { v.x = -v.x; v.y = -v.y; v.z = -v.z; }
      X[row] = v;
    }
  }
  {
    const float* src = s ? k : q;
    const int r0g = b * 512 + chunk * 64;
#pragma unroll
    for (int e = 0; e < 16; ++e) {
      const int idx = e * 256 + t;
      const int row = idx >> 6, c = idx & 63;
      float v = src[(size_t)(r0g + row) * 64 + c];
      if (!s) v += bp2[c];
      U[row][c] = v;
    }
  }
  __syncthreads();

  {
    const int al = t >> 2, qr = t & 3;
    const int a = chunk * 64 + al;
    const f32x4 xa = X[a];
    const float base0 = xa.x + b_p[0], base1 = xa.y + b_p[1], base2 = xa.z + b_p[2];
    float r0 = 0, r1 = 0, r2 = 0;
    float m00 = 0, m01 = 0, m02 = 0, m11 = 0, m12 = 0, m22 = 0;
#pragma unroll 8
    for (int jj = qr * 128; jj < qr * 128 + 128; ++jj) {
      const f32x4 xj = X[jj];
      const float h0 = fmaxf(0.f, base0 - xj.x);
      const float h1 = fmaxf(0.f, base1 - xj.y);
      const float h2 = fmaxf(0.f, base2 - xj.z);
      r0 += h0; r1 += h1; r2 += h2;
      if (s == 0) {
        m00 = fmaf(h0, h0, m00); m01 = fmaf(h0, h1, m01); m02 = fmaf(h0, h2, m02);
        m11 = fmaf(h1, h1, m11); m12 = fmaf(h1, h2, m12); m22 = fmaf(h2, h2, m22);
      }
    }
    redr[al][qr][0] = r0; redr[al][qr][1] = r1; redr[al][qr][2] = r2; redr[al][qr][3] = 0.f;
    mred[t][0] = m00; mred[t][1] = m01; mred[t][2] = m02;
    mred[t][3] = m11; mred[t][4] = m12; mred[t][5] = m22;
  }
  __syncthreads();

  if (t < 64) {
    float sx = 0, sy = 0, sz = 0;
#pragma unroll
    for (int p = 0; p < 4; ++p) { sx += redr[t][p][0]; sy += redr[t][p][1]; sz += redr[t][p][2]; }
    rfin[t][0] = sx; rfin[t][1] = sy; rfin[t][2] = sz; rfin[t][3] = 0.f;
    if (s == 0) {
#pragma unroll
      for (int cc = 0; cc < 6; ++cc)
        mred2[t][cc] = mred[t][cc] + mred[t + 64][cc] + mred[t + 128][cc] + mred[t + 192][cc];
    }
  }
  __syncthreads();

  if (s == 0 && t < 6) {
    float m = 0.f;
    for (int p = 0; p < 64; ++p) m += mred2[p][t];
    Mpart[bid * 12 + t] = m;
  }
  if (s == 0 && t >= 64 && t < 67) {
    const int tt = t - 64;
    float v = 0.f;
#pragma unroll 8
    for (int a = 0; a < 64; ++a) v += rfin[a][tt];
    Mpart[bid * 12 + 6 + tt] = v;
  }
  if (t < 192) {
    const int c = t & 63, tt = t >> 6;
    float xp = 0.f;
#pragma unroll 8
    for (int a = 0; a < 64; ++a) xp = fmaf(U[a][c], rfin[a][tt], xp);
    if (s) xp = -xp;
    XPp[((size_t)bid * 3 + tt) * 64 + c] = xp;
  }
  {
    const int c = t & 63, g = t >> 6;
    float su = 0.f, su2 = 0.f;
#pragma unroll
    for (int r = 0; r < 16; ++r) {
      const float v = U[g * 16 + r][c];
      su += v;
      su2 = fmaf(v, v, su2);
    }
    redn[t][0] = su; redn[t][1] = su2;
  }
  __syncthreads();
  if (t < 64) {
    float a0 = 0.f, a1v = 0.f;
#pragma unroll
    for (int p = 0; p < 4; ++p) { a0 += redn[t + 64 * p][0]; a1v += redn[t + 64 * p][1]; }
    SNp[((size_t)bid * 2 + 0) * 64 + t] = a0;
    SNp[((size_t)bid * 2 + 1) * 64 + t] = a1v;
  }

  __syncthreads();
  if (t == 0) {
    __threadfence();
    const unsigned int old = atomicAdd(counter, 1u);
    isLast = (old == 31u) ? 1u : 0u;
  }
  __syncthreads();
  if (isLast) {
    __threadfence();
    if (t < 6) {
      float m = 0.f;
#pragma unroll
      for (int p = 0; p < 16; ++p) m += Mpart[p * 12 + t];
      MfS[t] = m;
    }
    if (t >= 6 && t < 9) {
      const int tt = t - 6;
      float v = 0.f;
#pragma unroll
      for (int p = 0; p < 16; ++p) v += Mpart[p * 12 + 6 + tt];
      ShfS[tt] = v;
    }
    __syncthreads();
    if (t < 64) {
      const int c = t;
      float Su[2], Su2[2], Sk[2], Sk2[2];
#pragma unroll
      for (int bb = 0; bb < 2; ++bb) {
        float a0 = 0.f, a1v = 0.f, a2v = 0.f, a3 = 0.f;
#pragma unroll
        for (int p = 0; p < 8; ++p) {
          const int blkU = bb * 8 + p;
          const int blkK = 16 + bb * 8 + p;
          a0 += SNp[((size_t)blkU * 2 + 0) * 64 + c];
          a1v += SNp[((size_t)blkU * 2 + 1) * 64 + c];
          a2v += SNp[((size_t)blkK * 2 + 0) * 64 + c];
          a3 += SNp[((size_t)blkK * 2 + 1) * 64 + c];
        }
        Su[bb] = a0; Su2[bb] = a1v; Sk[bb] = a2v; Sk2[bb] = a3;
      }
      float URd0 = 0.f, URd1 = 0.f, URd2 = 0.f;
#pragma unroll
      for (int blk = 0; blk < 32; ++blk) {
        URd0 += XPp[((size_t)blk * 3 + 0) * 64 + c];
        URd1 += XPp[((size_t)blk * 3 + 1) * 64 + c];
        URd2 += XPp[((size_t)blk * 3 + 2) * 64 + c];
      }
      const float P0t = Wp2[c * 3 + 0], P1t = Wp2[c * 3 + 1], P2t = Wp2[c * 3 + 2];
      const float Nf = 512.f, invM = 1.f / 524288.f;
      float S1 = 0.f, Q2 = 0.f;
#pragma unroll
      for (int bb = 0; bb < 2; ++bb) {
        S1 += Nf * (Su[bb] - Sk[bb]);
        Q2 += Nf * Su2[bb] - 2.f * Su[bb] * Sk[bb] + Nf * Sk2[bb];
      }
      const float Xc = P0t * URd0 + P1t * URd1 + P2t * URd2;
      S1 += P0t * ShfS[0] + P1t * ShfS[1] + P2t * ShfS[2];
      const float Hm = P0t * P0t * MfS[0] + 2.f * P0t * P1t * MfS[1] + 2.f * P0t * P2t * MfS[2]
                     + P1t * P1t * MfS[3] + 2.f * P1t * P2t * MfS[4] + P2t * P2t * MfS[5];
      const float E1 = S1 * invM;
      const float E2 = (Q2 + 2.f * Xc + Hm) * invM;
      const float var = E2 - E1 * E1;
      const float rstd = rsqrtf(var + 1e-5f);
      const float A2 = g_w[c] * rstd;
      a2o[c] = A2;
      be2o[c] = b_w[c] - E1 * A2;
      PtT[0 * 64 + c] = A2 * P0t;
      PtT[1 * 64 + c] = A2 * P1t;
      PtT[2 * 64 + c] = A2 * P2t;
    }
  }
}

// ---------------------------------------------------------------------------
// k3: fused main — round-5 skeleton (1 i/block, LDS stage-A consts, grid
// 1024, direct out) + kv-only prefetch + bias-in-C-init + exp2-direct.
// ---------------------------------------------------------------------------
__launch_bounds__(256)
__global__ void k3_main(const float* __restrict__ q, const float* __restrict__ kk_,
                        const float* __restrict__ vT, const float* __restrict__ hpa,
                        const float* __restrict__ a2g, const float* __restrict__ be2g,
                        const float* __restrict__ PtTg,
                        const uint16_t* __restrict__ W1bf, const uint16_t* __restrict__ W2bf,
                        const float* __restrict__ bp2, const float* __restrict__ Wp2,
                        const float* __restrict__ b_p, const float* __restrict__ bw1g,
                        const float* __restrict__ bw2g, float* __restrict__ out) {
  const int bid = blockIdx.x;
  const int b = bid >> 9, i = bid & 511;
  const int t = threadIdx.x;
  const int wid = t >> 6, l = t & 63;
  const int lm = l & 15, lq = l >> 4;

  __shared__ __align__(16) uint16_t W1l[4096];
  __shared__ __align__(16) uint16_t W2l[4096];
  __shared__ __align__(16) uint16_t H2[4][16][76];
  __shared__ __align__(16) float P0[64];
  __shared__ __align__(16) float a2s[64];
  __shared__ __align__(16) float Pts[3][64];
  __shared__ __align__(16) float comb[4][64][2];

  {
    *(bf16x8*)(&W1l[t * 16])     = *(const bf16x8*)(W1bf + t * 16);
    *(bf16x8*)(&W1l[t * 16 + 8]) = *(const bf16x8*)(W1bf + t * 16 + 8);
    *(bf16x8*)(&W2l[t * 16])     = *(const bf16x8*)(W2bf + t * 16);
    *(bf16x8*)(&W2l[t * 16 + 8]) = *(const bf16x8*)(W2bf + t * 16 + 8);
  }
  if (t < 64) {
    const float a2v = a2g[t];
    a2s[t] = a2v;
    P0[t] = fmaf(a2v, q[(size_t)(b * 512 + i) * 64 + t] + bp2[t], be2g[t]);
  } else {
    const int idx = t - 64;
    Pts[idx >> 6][idx & 63] = PtTg[idx];
  }

  const f32x4 hi = *(const f32x4*)(hpa + (size_t)(b * 512 + i) * 4);
  const float bb0 = b_p[0], bb1 = b_p[1], bb2 = b_p[2];
  const float LOG2E = 1.4426950408889634f;

  float bw1r[4], bw2l[4], wpa[4], wpb[4], wpc[4];
#pragma unroll
  for (int nt = 0; nt < 4; ++nt) {
    const int c = 16 * nt + lm;
    bw1r[nt] = bw1g[c];
    bw2l[nt] = bw2g[c] * LOG2E;
    wpa[nt] = Wp2[c * 3 + 0];
    wpb[nt] = Wp2[c * 3 + 1];
    wpc[nt] = Wp2[c * 3 + 2];
  }

  float l_[4] = {0.f, 0.f, 0.f, 0.f};
  float acc_[4] = {0.f, 0.f, 0.f, 0.f};

  __syncthreads();

  const float* kbase = kk_ + (size_t)(b * 512) * 64;
  const float* hbase = hpa + (size_t)(b * 512) * 4;
  const float* vTb = vT + (size_t)b * 64 * 512;

  // prefetch k-row for it=0
  f32x4 kvA[2][2];
  {
    const int j0 = wid * 16 + lm;
#pragma unroll
    for (int ks = 0; ks < 2; ++ks) {
      kvA[ks][0] = *(const f32x4*)(kbase + (size_t)j0 * 64 + 32 * ks + 8 * lq);
      kvA[ks][1] = *(const f32x4*)(kbase + (size_t)j0 * 64 + 32 * ks + 8 * lq + 4);
    }
  }

  for (int it = 0; it < 8; ++it) {
    const int jb = it * 64 + wid * 16;
    const int j = jb + lm;
    const int j2 = jb + 4 * lq;

    // prefetch NEXT iteration's k-row (only this; all else stays lean)
    f32x4 kvN[2][2];
    if (it < 7) {
      const int jn = j + 64;
#pragma unroll
      for (int ks = 0; ks < 2; ++ks) {
        kvN[ks][0] = *(const f32x4*)(kbase + (size_t)jn * 64 + 32 * ks + 8 * lq);
        kvN[ks][1] = *(const f32x4*)(kbase + (size_t)jn * 64 + 32 * ks + 8 * lq + 4);
      }
    }

    const f32x4 hj = *(const f32x4*)(hbase + j * 4);
    f32x4 hjr[4];
#pragma unroll
    for (int r = 0; r < 4; ++r) hjr[r] = *(const f32x4*)(hbase + (j2 + r) * 4);
    f32x4 vv[4];
#pragma unroll
    for (int nt = 0; nt < 4; ++nt)
      vv[nt] = *(const f32x4*)(vTb + (size_t)(16 * nt + lm) * 512 + j2);

    // ---- stage A: x = relu(a2*qk + b2) as A-fragments ----
    const float h0 = fmaxf(0.f, hi.x - hj.x + bb0);
    const float h1 = fmaxf(0.f, hi.y - hj.y + bb1);
    const float h2v = fmaxf(0.f, hi.z - hj.z + bb2);

    FragU A1[2];
#pragma unroll
    for (int ks = 0; ks < 2; ++ks) {
      const int c0 = 32 * ks + 8 * lq;
      f32x4 pv[2], av[2], t0[2], t1[2], t2[2];
      pv[0] = *(const f32x4*)(P0 + c0);        pv[1] = *(const f32x4*)(P0 + c0 + 4);
      av[0] = *(const f32x4*)(a2s + c0);       av[1] = *(const f32x4*)(a2s + c0 + 4);
      t0[0] = *(const f32x4*)(&Pts[0][c0]);    t0[1] = *(const f32x4*)(&Pts[0][c0 + 4]);
      t1[0] = *(const f32x4*)(&Pts[1][c0]);    t1[1] = *(const f32x4*)(&Pts[1][c0 + 4]);
      t2[0] = *(const f32x4*)(&Pts[2][c0]);    t2[1] = *(const f32x4*)(&Pts[2][c0 + 4]);
      float x[8];
#pragma unroll
      for (int e = 0; e < 8; ++e) {
        const int hh = e >> 2, e4 = e & 3;
        float xv = pv[hh][e4] - av[hh][e4] * kvA[ks][hh][e4];
        xv = fmaf(t0[hh][e4], h0, xv);
        xv = fmaf(t1[hh][e4], h1, xv);
        xv = fmaf(t2[hh][e4], h2v, xv);
        x[e] = fmaxf(0.f, xv);
      }
      A1[ks].u[0] = pk_bf16(x[0], x[1]);
      A1[ks].u[1] = pk_bf16(x[2], x[3]);
      A1[ks].u[2] = pk_bf16(x[4], x[5]);
      A1[ks].u[3] = pk_bf16(x[6], x[7]);
    }

    // ---- GEMM1 (bias in C-init) ----
    f32x4 d1[4];
#pragma unroll
    for (int nt = 0; nt < 4; ++nt) {
      FragU b0, b1;
      b0.f = *(const bf16x8*)(&W1l[((nt * 2 + 0) * 64 + l) * 8]);
      b1.f = *(const bf16x8*)(&W1l[((nt * 2 + 1) * 64 + l) * 8]);
      f32x4 z = {bw1r[nt], bw1r[nt], bw1r[nt], bw1r[nt]};
      z = __builtin_amdgcn_mfma_f32_16x16x32_bf16(A1[0].f, b0.f, z, 0, 0, 0);
      z = __builtin_amdgcn_mfma_f32_16x16x32_bf16(A1[1].f, b1.f, z, 0, 0, 0);
      d1[nt] = z;
    }

    // ---- relu, repack h2 to bf16 LDS (per-wave private, pad 76) ----
    uint16_t (*h2w)[76] = H2[wid];
#pragma unroll
    for (int nt = 0; nt < 4; ++nt) {
      const uint32_t u01 = pk_bf16(fmaxf(0.f, d1[nt][0]), fmaxf(0.f, d1[nt][1]));
      const uint32_t u23 = pk_bf16(fmaxf(0.f, d1[nt][2]), fmaxf(0.f, d1[nt][3]));
      const int col = 16 * nt + lm;
      h2w[4 * lq + 0][col] = (uint16_t)(u01 & 0xffffu);
      h2w[4 * lq + 1][col] = (uint16_t)(u01 >> 16);
      h2w[4 * lq + 2][col] = (uint16_t)(u23 & 0xffffu);
      h2w[4 * lq + 3][col] = (uint16_t)(u23 >> 16);
    }

    FragU A2[2];
    A2[0].f = *(const bf16x8*)(&h2w[lm][8 * lq]);
    A2[1].f = *(const bf16x8*)(&h2w[lm][32 + 8 * lq]);

    // ---- GEMM2 (log2e-scaled W2, bias*log2e in C-init) ----
    f32x4 d2[4];
#pragma unroll
    for (int nt = 0; nt < 4; ++nt) {
      FragU b0, b1;
      b0.f = *(const bf16x8*)(&W2l[((nt * 2 + 0) * 64 + l) * 8]);
      b1.f = *(const bf16x8*)(&W2l[((nt * 2 + 1) * 64 + l) * 8]);
      f32x4 z = {bw2l[nt], bw2l[nt], bw2l[nt], bw2l[nt]};
      z = __builtin_amdgcn_mfma_f32_16x16x32_bf16(A2[0].f, b0.f, z, 0, 0, 0);
      z = __builtin_amdgcn_mfma_f32_16x16x32_bf16(A2[1].f, b1.f, z, 0, 0, 0);
      d2[nt] = z;
    }

    // ---- hr for this lane's 4 output j-rows ----
    float hr0[4], hr1[4], hr2[4];
#pragma unroll
    for (int r = 0; r < 4; ++r) {
      hr0[r] = fmaxf(0.f, hi.x - hjr[r].x + bb0);
      hr1[r] = fmaxf(0.f, hi.y - hjr[r].y + bb1);
      hr2[r] = fmaxf(0.f, hi.z - hjr[r].z + bb2);
    }

    // ---- no-max softmax accumulation (exp2 direct) ----
#pragma unroll
    for (int nt = 0; nt < 4; ++nt) {
      float p[4], val[4];
#pragma unroll
      for (int r = 0; r < 4; ++r) {
        p[r] = __builtin_amdgcn_exp2f(d2[nt][r]);
        float v0 = vv[nt][r];
        v0 = fmaf(wpa[nt], hr0[r], v0);
        v0 = fmaf(wpb[nt], hr1[r], v0);
        v0 = fmaf(wpc[nt], hr2[r], v0);
        val[r] = v0;
      }
      l_[nt] += (p[0] + p[1]) + (p[2] + p[3]);
      float a = acc_[nt];
      a = fmaf(p[0], val[0], a);
      a = fmaf(p[1], val[1], a);
      a = fmaf(p[2], val[2], a);
      a = fmaf(p[3], val[3], a);
      acc_[nt] = a;
    }

    // rotate prefetch
    if (it < 7) {
#pragma unroll
      for (int ks = 0; ks < 2; ++ks) {
        kvA[ks][0] = kvN[ks][0];
        kvA[ks][1] = kvN[ks][1];
      }
    }
  }

  // ---- combine (linear): shfl over lq groups, then across waves ----
#pragma unroll
  for (int nt = 0; nt < 4; ++nt) {
    l_[nt] += __shfl_xor(l_[nt], 16);
    acc_[nt] += __shfl_xor(acc_[nt], 16);
    l_[nt] += __shfl_xor(l_[nt], 32);
    acc_[nt] += __shfl_xor(acc_[nt], 32);
  }
  if (lq == 0) {
#pragma unroll
    for (int nt = 0; nt < 4; ++nt) {
      comb[wid][16 * nt + lm][0] = l_[nt];
      comb[wid][16 * nt + lm][1] = acc_[nt];
    }
  }
  __syncthreads();
  if (t < 64) {
    float L = 0.f, A = 0.f;
#pragma unroll
    for (int w = 0; w < 4; ++w) {
      L += comb[w][t][0];
      A += comb[w][t][1];
    }
    out[(size_t)(b * 512 + i) * 64 + t] = A / L;
  }
}

// ---------------------------------------------------------------------------
extern "C" void kernel_launch(void* const* d_in, const int* in_sizes, int n_in,
                              void* d_out, int out_size, void* d_ws, size_t ws_size,
                              hipStream_t stream) {
  (void)in_sizes; (void)n_in; (void)out_size; (void)ws_size;
  const float* pos = (const float*)d_in[0];
  const float* cf  = (const float*)d_in[1];
  const float* Wq  = (const float*)d_in[2];
  const float* bq  = (const float*)d_in[3];
  const float* Wk  = (const float*)d_in[4];
  const float* bk  = (const float*)d_in[5];
  const float* Wv  = (const float*)d_in[6];
  const float* bv  = (const float*)d_in[7];
  const float* Wp1 = (const float*)d_in[8];
  // d_in[9] = bp1: cancels analytically (gamma1 == b_p exactly)
  const float* g_p = (const float*)d_in[10];
  const float* b_p = (const float*)d_in[11];
  const float* Wp2 = (const float*)d_in[12];
  const float* bp2 = (const float*)d_in[13];
  const float* g_w = (const float*)d_in[14];
  const float* b_w = (const float*)d_in[15];
  const float* Ww1 = (const float*)d_in[16];
  const float* bw1 = (const float*)d_in[17];
  const float* Ww2 = (const float*)d_in[18];
  const float* bw2 = (const float*)d_in[19];

  char* ws = (char*)d_ws;
  uint16_t*     W1bf = (uint16_t*)(ws + 0);        // 8 KB
  uint16_t*     W2bf = (uint16_t*)(ws + 8192);     // 8 KB (log2e-scaled)
  float*        a1w  = (float*)(ws + 16384);
  unsigned int* cnt  = (unsigned int*)(ws + 16640);
  float*        hpaw = (float*)(ws + 16896);       // [1024][4]
  float*        qw   = (float*)(ws + 33280);       // [1024][64]
  float*        kw   = (float*)(ws + 295424);      // [1024][64]
  float*        vTw  = (float*)(ws + 557568);      // [2][64][512]
  float*        a2w  = (float*)(ws + 819712);
  float*        be2w = (float*)(ws + 819968);
  float*        PtTw = (float*)(ws + 820224);      // [3][64]
  float*        Mpw  = (float*)(ws + 821248);      // [32][12]
  float*        XPpw = (float*)(ws + 823040);      // [32][3][64]
  float*        SNpw = (float*)(ws + 847872);      // [32][2][64]

  kP<<<dim3(258), dim3(256), 0, stream>>>(cf, pos, Wq, Wk, Wv, bq, bk, bv,
                                          Ww1, Ww2, Wp1, g_p, bp2,
                                          qw, kw, vTw, W1bf, W2bf, a1w, cnt);
  kB<<<dim3(32), dim3(256), 0, stream>>>(pos, a1w, Wp1, b_p, qw, kw, bp2,
                                         g_w, b_w, Wp2,
                                         hpaw, Mpw, XPpw, SNpw, cnt,
                                         a2w, be2w, PtTw);
  k3_main<<<dim3(1024), dim3(256), 0, stream>>>(qw, kw, vTw, hpaw, a2w, be2w, PtTw,
                                                W1bf, W2bf, bp2, Wp2, b_p, bw1, bw2,
                                                (float*)d_out);
}